// Round 1
// baseline (407.790 us; speedup 1.0000x reference)
//
#include <hip/hip_runtime.h>
#include <stdint.h>

#define BATCH 32
#define SEQ   1024
#define DIM   768
#define NQKV  2304   // 3*DIM

typedef unsigned short u16;
typedef __attribute__((ext_vector_type(8))) short short8;   // 8 x bf16 (4 VGPRs)
typedef __attribute__((ext_vector_type(4))) float f32x4;

// fp32 -> bf16 round-to-nearest-even (finite inputs)
static __device__ __forceinline__ u16 f2bf(float f) {
  uint32_t u = __float_as_uint(f);
  uint32_t r = (u + 0x7fffu + ((u >> 16) & 1u)) >> 16;
  return (u16)r;
}

static __device__ __forceinline__ void gload_lds16(const void* g, void* l) {
  __builtin_amdgcn_global_load_lds(
      (const __attribute__((address_space(1))) unsigned int*)g,
      (__attribute__((address_space(3))) unsigned int*)l, 16, 0, 0);
}

// ---------------------------------------------------------------------------
// gemm_bt core: C[128x128] += A[128xK] * B^T, A and Bt both row-major [x][k].
// BK=32, 4 waves (256 thr), each wave 64x64 via 4x4 frags of 16x16x32 bf16.
// LDS: As/Bs each 2 buffers of 128*32 bf16 (8KB), staged via global_load_lds.
// ---------------------------------------------------------------------------
static __device__ __forceinline__ void gemm_bt_core(
    const u16* __restrict__ Ab, int lda,
    const u16* __restrict__ Bb, int ldb,
    int KT, u16* As, u16* Bs, f32x4 (&acc)[4][4])
{
  const int tid  = threadIdx.x;
  const int wid  = tid >> 6;
  const int lane = tid & 63;
  const int wrow = (wid >> 1) * 64;
  const int wcol = (wid & 1) * 64;

  #pragma unroll
  for (int m = 0; m < 4; ++m)
    #pragma unroll
    for (int n = 0; n < 4; ++n)
      acc[m][n] = (f32x4){0.f, 0.f, 0.f, 0.f};

  const int srow = tid >> 2;        // 0..63
  const int scol = (tid & 3) * 8;   // 0,8,16,24

  auto stage = [&](const u16* gb, int ld, u16* lds, int buf, int k0) {
    #pragma unroll
    for (int i = 0; i < 2; ++i) {
      const void* g = (const void*)(gb + (size_t)(i * 64 + srow) * ld + (k0 + scol));
      void* l = (void*)((char*)lds + buf * 8192 + i * 4096 + wid * 1024);
      gload_lds16(g, l);
    }
  };

  auto compute = [&](int buf) {
    const u16* a_ = As + buf * 4096;
    const u16* b_ = Bs + buf * 4096;
    short8 afr[4], bfr[4];
    const int ro = (lane & 15) * 32 + (lane >> 4) * 8;
    #pragma unroll
    for (int m = 0; m < 4; ++m)
      afr[m] = *(const short8*)(a_ + (wrow + m * 16) * 32 + ro);
    #pragma unroll
    for (int n = 0; n < 4; ++n)
      bfr[n] = *(const short8*)(b_ + (wcol + n * 16) * 32 + ro);
    #pragma unroll
    for (int m = 0; m < 4; ++m)
      #pragma unroll
      for (int n = 0; n < 4; ++n)
        acc[m][n] = __builtin_amdgcn_mfma_f32_16x16x32_bf16(afr[m], bfr[n], acc[m][n], 0, 0, 0);
  };

  stage(Ab, lda, As, 0, 0);
  stage(Bb, ldb, Bs, 0, 0);
  asm volatile("s_waitcnt vmcnt(0)" ::: "memory");
  __syncthreads();
  int cur = 0;
  for (int kt = 0; kt < KT; ++kt) {
    if (kt + 1 < KT) {
      stage(Ab, lda, As, cur ^ 1, (kt + 1) * 32);
      stage(Bb, ldb, Bs, cur ^ 1, (kt + 1) * 32);
    }
    compute(cur);
    asm volatile("s_waitcnt vmcnt(0)" ::: "memory");
    __syncthreads();
    cur ^= 1;
  }
}

// ---------------------------------------------------------------------------
// x fp32 -> bf16
__global__ __launch_bounds__(256)
void cvt_x_kernel(const float* __restrict__ X, u16* __restrict__ Xb) {
  const size_t i = ((size_t)blockIdx.x * 256 + threadIdx.x) * 8;
  f32x4 a = *(const f32x4*)(X + i);
  f32x4 b = *(const f32x4*)(X + i + 4);
  short8 r;
  #pragma unroll
  for (int j = 0; j < 4; ++j) { r[j] = (short)f2bf(a[j]); r[j + 4] = (short)f2bf(b[j]); }
  *(short8*)(Xb + i) = r;
}

// W [768][2304] fp32 -> Wt [2304][768] bf16
__global__ void wt_kernel(const float* __restrict__ W, u16* __restrict__ Wt) {
  __shared__ u16 t[32][33];
  const int n0 = blockIdx.x * 32, k0 = blockIdx.y * 32;
  const int tx = threadIdx.x, ty = threadIdx.y;
  #pragma unroll
  for (int r = 0; r < 4; ++r)
    t[ty + r * 8][tx] = f2bf(W[(size_t)(k0 + ty + r * 8) * NQKV + n0 + tx]);
  __syncthreads();
  #pragma unroll
  for (int r = 0; r < 4; ++r)
    Wt[(size_t)(n0 + ty + r * 8) * DIM + k0 + tx] = t[tx][ty + r * 8];
}

// v (inside qkv, col offset 1536) -> vT [b][d][t] bf16
__global__ void vt_kernel(const u16* __restrict__ qkv, u16* __restrict__ vT) {
  __shared__ u16 t[32][33];
  const int b = blockIdx.z;
  const int t0 = blockIdx.y * 32, d0 = blockIdx.x * 32;
  const int tx = threadIdx.x, ty = threadIdx.y;
  const u16* src = qkv + (size_t)b * SEQ * NQKV + 2 * DIM;
  #pragma unroll
  for (int r = 0; r < 4; ++r)
    t[ty + r * 8][tx] = src[(size_t)(t0 + ty + r * 8) * NQKV + d0 + tx];
  __syncthreads();
  u16* dst = vT + (size_t)b * DIM * SEQ;
  #pragma unroll
  for (int r = 0; r < 4; ++r)
    dst[(size_t)(d0 + ty + r * 8) * SEQ + t0 + tx] = t[tx][ty + r * 8];
}

// qkv = x @ W + b, written bf16 with decay folded:
//   q *= alpha^s / sqrt(d),  k *= alpha^(-s),  v unscaled
__global__ __launch_bounds__(256)
void qkv_gemm_kernel(const u16* __restrict__ Xb, const u16* __restrict__ Wt,
                     const float* __restrict__ bias, u16* __restrict__ qkv) {
  __shared__ u16 As[2 * 4096];
  __shared__ u16 Bs[2 * 4096];
  f32x4 acc[4][4];
  const int mt = blockIdx.y, nt = blockIdx.x;
  gemm_bt_core(Xb + (size_t)mt * 128 * DIM, DIM,
               Wt + (size_t)nt * 128 * DIM, DIM, DIM / 32, As, Bs, acc);

  const int tid = threadIdx.x, wid = tid >> 6, lane = tid & 63;
  const int wrow = (wid >> 1) * 64, wcol = (wid & 1) * 64;
  const int lr = (lane >> 4) * 4, lc = lane & 15;
  const float L2A = -0.014499570f;    // log2(0.99)
  const float ISD = 0.03608439182f;   // 1/sqrt(768)
  #pragma unroll
  for (int m = 0; m < 4; ++m) {
    #pragma unroll
    for (int n = 0; n < 4; ++n) {
      const int gcol = nt * 128 + wcol + n * 16 + lc;
      const float bv = bias[gcol];
      #pragma unroll
      for (int j = 0; j < 4; ++j) {
        const int grow = mt * 128 + wrow + m * 16 + lr + j;
        const int s = grow & (SEQ - 1);
        float v = acc[m][n][j] + bv;
        float scale = (gcol < DIM)     ? exp2f((float)s * L2A) * ISD
                    : (gcol < 2 * DIM) ? exp2f(-(float)s * L2A)
                                       : 1.0f;
        qkv[(size_t)grow * NQKV + gcol] = f2bf(v * scale);
      }
    }
  }
}

// S = q~ @ k~^T per batch, lower-triangular tiles only; strict-upper zeroed
__global__ __launch_bounds__(256)
void qk_gemm_kernel(const u16* __restrict__ qkv, u16* __restrict__ S) {
  __shared__ u16 As[2 * 4096];
  __shared__ u16 Bs[2 * 4096];
  f32x4 acc[4][4];
  const int b = blockIdx.y;
  const int p = blockIdx.x;        // 0..35 triangular pair
  int it = 0;
  while ((it + 1) * (it + 2) / 2 <= p) ++it;
  const int jt = p - it * (it + 1) / 2;
  const u16* Ab = qkv + (size_t)(b * SEQ + it * 128) * NQKV;        // q rows
  const u16* Bb = qkv + (size_t)(b * SEQ + jt * 128) * NQKV + DIM;  // k rows
  gemm_bt_core(Ab, NQKV, Bb, NQKV, DIM / 32, As, Bs, acc);

  u16* Sb = S + (size_t)b * SEQ * SEQ;
  const int tid = threadIdx.x, wid = tid >> 6, lane = tid & 63;
  const int wrow = (wid >> 1) * 64, wcol = (wid & 1) * 64;
  const int lr = (lane >> 4) * 4, lc = lane & 15;
  #pragma unroll
  for (int m = 0; m < 4; ++m) {
    #pragma unroll
    for (int n = 0; n < 4; ++n) {
      const int c = jt * 128 + wcol + n * 16 + lc;
      #pragma unroll
      for (int j = 0; j < 4; ++j) {
        const int r = it * 128 + wrow + m * 16 + lr + j;
        float v = acc[m][n][j];
        if (c > r) v = 0.f;   // strict upper (only on diagonal tiles)
        Sb[(size_t)r * SEQ + c] = f2bf(v);
      }
    }
  }
}

// out = S @ v per batch (K-loop stops at the causal boundary)
__global__ __launch_bounds__(256)
void pv_gemm_kernel(const u16* __restrict__ S, const u16* __restrict__ vT,
                    float* __restrict__ out) {
  __shared__ u16 As[2 * 4096];
  __shared__ u16 Bs[2 * 4096];
  f32x4 acc[4][4];
  const int b = blockIdx.z, it = blockIdx.y, nt = blockIdx.x;
  const u16* Ab = S + (size_t)b * SEQ * SEQ + (size_t)it * 128 * SEQ;
  const u16* Bb = vT + (size_t)b * DIM * SEQ + (size_t)nt * 128 * SEQ;
  gemm_bt_core(Ab, SEQ, Bb, SEQ, (it + 1) * 4, As, Bs, acc);

  float* Ob = out + (size_t)b * SEQ * DIM;
  const int tid = threadIdx.x, wid = tid >> 6, lane = tid & 63;
  const int wrow = (wid >> 1) * 64, wcol = (wid & 1) * 64;
  const int lr = (lane >> 4) * 4, lc = lane & 15;
  #pragma unroll
  for (int m = 0; m < 4; ++m) {
    #pragma unroll
    for (int n = 0; n < 4; ++n) {
      const int c = nt * 128 + wcol + n * 16 + lc;
      #pragma unroll
      for (int j = 0; j < 4; ++j) {
        const int r = it * 128 + wrow + m * 16 + lr + j;
        Ob[(size_t)r * DIM + c] = acc[m][n][j];
      }
    }
  }
}

extern "C" void kernel_launch(void* const* d_in, const int* in_sizes, int n_in,
                              void* d_out, int out_size, void* d_ws, size_t ws_size,
                              hipStream_t stream) {
  const float* x    = (const float*)d_in[0];
  const float* W    = (const float*)d_in[1];
  const float* bias = (const float*)d_in[2];
  float* out = (float*)d_out;

  char* ws = (char*)d_ws;
  const size_t SZ_QKV = (size_t)BATCH * SEQ * NQKV * 2;  // 150,994,944
  const size_t SZ_WT  = (size_t)NQKV * DIM * 2;          //   3,538,944
  const size_t SZ_VT  = (size_t)BATCH * DIM * SEQ * 2;   //  50,331,648
  const size_t SZ_S   = (size_t)BATCH * SEQ * SEQ * 2;   //  67,108,864
  const size_t SZ_XB  = (size_t)BATCH * SEQ * DIM * 2;   //  50,331,648
  u16* qkv = (u16*)(ws);
  u16* Wt  = (u16*)(ws + SZ_QKV);
  u16* vT  = (u16*)(ws + SZ_QKV + SZ_WT);
  u16* Smt = (u16*)(ws + SZ_QKV + SZ_WT + SZ_VT);
  u16* Xb  = (u16*)(ws + SZ_QKV + SZ_WT + SZ_VT + SZ_S);
  if (ws_size < SZ_QKV + SZ_WT + SZ_VT + SZ_S + SZ_XB) return;  // need ~322MB

  cvt_x_kernel<<<dim3((BATCH * SEQ * DIM / 8) / 256), 256, 0, stream>>>(x, Xb);
  wt_kernel<<<dim3(NQKV / 32, DIM / 32), dim3(32, 8), 0, stream>>>(W, Wt);
  qkv_gemm_kernel<<<dim3(NQKV / 128, BATCH * SEQ / 128), 256, 0, stream>>>(Xb, Wt, bias, qkv);
  vt_kernel<<<dim3(DIM / 32, SEQ / 32, BATCH), dim3(32, 8), 0, stream>>>(qkv, vT);
  qk_gemm_kernel<<<dim3(36, BATCH), 256, 0, stream>>>(qkv, Smt);
  pv_gemm_kernel<<<dim3(DIM / 128, SEQ / 128, BATCH), 256, 0, stream>>>(Smt, vT, out);
}

// Round 2
// 366.796 us; speedup vs baseline: 1.1118x; 1.1118x over previous
//
#include <hip/hip_runtime.h>
#include <stdint.h>

#define BATCH 32
#define SEQ   1024
#define DIM   768
#define NQKV  2304   // 3*DIM

typedef unsigned short u16;
typedef __attribute__((ext_vector_type(8))) short short8;   // 8 x bf16 (4 VGPRs)
typedef __attribute__((ext_vector_type(4))) float f32x4;

// fp32 -> bf16 round-to-nearest-even (finite inputs)
static __device__ __forceinline__ u16 f2bf(float f) {
  uint32_t u = __float_as_uint(f);
  uint32_t r = (u + 0x7fffu + ((u >> 16) & 1u)) >> 16;
  return (u16)r;
}

static __device__ __forceinline__ void gload_lds16(const void* g, void* l) {
  __builtin_amdgcn_global_load_lds(
      (const __attribute__((address_space(1))) unsigned int*)g,
      (__attribute__((address_space(3))) unsigned int*)l, 16, 0, 0);
}

// raw barrier: no compiler-inserted vmcnt(0) drain, but block memory-op reordering
#define CFENCE asm volatile("" ::: "memory")
static __device__ __forceinline__ void barrier_raw() {
  CFENCE; __builtin_amdgcn_s_barrier(); CFENCE;
}

// ===========================================================================
// 256x256 deep-pipelined bt-GEMM for qkv:  C = A[256xK] * B[256xK]^T
// BK=32, ring-of-4 LDS K-tile buffers, 8 waves (2M x 4N), per-wave 128x64.
// Counted vmcnt, raw barriers, T2 swizzle, T5 setprio, T1 XCD swizzle.
// ===========================================================================
__global__ __launch_bounds__(512, 2)
void qkv256_kernel(const u16* __restrict__ Xb, const u16* __restrict__ Wt,
                   const float* __restrict__ bias, u16* __restrict__ qkv) {
  extern __shared__ char smem[];        // 131072 bytes
  char* smemA = smem;                    // 4 rings * 16384 B
  char* smemB = smem + 65536;            // 4 rings * 16384 B

  // bijective XCD swizzle: 1152 blocks, 1152 % 8 == 0
  const int bid = blockIdx.x;
  const int swz = (bid & 7) * (1152 / 8) + (bid >> 3);
  const int mt = swz / 9;                // 0..127  (rows of C, 256 each)
  const int nt = swz % 9;                // 0..8    (cols of C, 256 each)

  const int tid  = threadIdx.x;
  const int wid  = tid >> 6;
  const int lane = tid & 63;
  const int wm   = wid >> 2;             // 0..1  -> rows wm*128..+128
  const int wn   = wid & 3;              // 0..3  -> cols wn*64..+64

  const u16* Ag = Xb + (size_t)mt * 256 * DIM;
  const u16* Bg = Wt + (size_t)nt * 256 * DIM;

  f32x4 acc[8][4];
  #pragma unroll
  for (int m = 0; m < 8; ++m)
    #pragma unroll
    for (int n = 0; n < 4; ++n)
      acc[m][n] = (f32x4){0.f, 0.f, 0.f, 0.f};

  // stage one half-tile (128 rows x 32 k) of tile kt into ring buffer.
  // LDS dest is linear (thread t -> chunk t); global source is inverse-swizzled
  // so that reads with the same swizzle see linear data (rule #21).
  auto stage = [&](const u16* gb, char* lsbase, int ring, int half, int kt) {
    const int doff = tid << 4;                                   // 0..8191
    const int loff = doff ^ (((doff >> 7) & 3) << 4);            // involution
    const int row  = loff >> 6;                                  // 0..127
    const int colb = loff & 63;                                  // byte in row
    const char* src = (const char*)gb +
        ((size_t)(half * 128 + row) * DIM + (size_t)kt * 32) * 2 + colb;
    char* dst = lsbase + ring * 16384 + half * 8192 + (wid << 10);  // wave-uniform
    gload_lds16(src, dst);
  };

  const int NT = DIM / 32;               // 24 K-tiles

  // prologue: stage tiles 0,1,2 (rings 0,1,2)
  for (int t = 0; t < 3; ++t) {
    stage(Ag, smemA, t, 0, t);
    stage(Ag, smemA, t, 1, t);
    stage(Bg, smemB, t, 0, t);
    stage(Bg, smemB, t, 1, t);
  }
  asm volatile("s_waitcnt vmcnt(8)" ::: "memory");   // tile 0 landed
  barrier_raw();

  const int lrow = lane & 15;
  const int c0   = lane >> 4;

  for (int T = 0; T < NT; ++T) {
    const int ring = T & 3;
    const char* abase = smemA + ring * 16384 + wm * 8192;
    const char* bbase = smemB + ring * 16384 + (wn >> 1) * 8192;

    // ---- phase 0: read B frags + A frags m0..3, stage A-halves of T+3 ----
    short8 bf[4], af[4];
    #pragma unroll
    for (int n = 0; n < 4; ++n) {
      const int row = (wn & 1) * 64 + n * 16 + lrow;
      const int c = c0 ^ ((row >> 1) & 3);
      bf[n] = *(const short8*)(bbase + row * 64 + c * 16);
    }
    #pragma unroll
    for (int m = 0; m < 4; ++m) {
      const int row = m * 16 + lrow;
      const int c = c0 ^ ((row >> 1) & 3);
      af[m] = *(const short8*)(abase + row * 64 + c * 16);
    }
    if (T + 3 < NT) {
      stage(Ag, smemA, (T + 3) & 3, 0, T + 3);
      stage(Ag, smemA, (T + 3) & 3, 1, T + 3);
    }
    barrier_raw();
    __builtin_amdgcn_s_setprio(1);
    #pragma unroll
    for (int m = 0; m < 4; ++m)
      #pragma unroll
      for (int n = 0; n < 4; ++n)
        acc[m][n] = __builtin_amdgcn_mfma_f32_16x16x32_bf16(af[m], bf[n], acc[m][n], 0, 0, 0);
    __builtin_amdgcn_s_setprio(0);
    barrier_raw();

    // ---- phase 1: read A frags m4..7, stage B-halves of T+3 ----
    #pragma unroll
    for (int m = 0; m < 4; ++m) {
      const int row = (m + 4) * 16 + lrow;
      const int c = c0 ^ ((row >> 1) & 3);
      af[m] = *(const short8*)(abase + row * 64 + c * 16);
    }
    if (T + 3 < NT) {
      stage(Bg, smemB, (T + 3) & 3, 0, T + 3);
      stage(Bg, smemB, (T + 3) & 3, 1, T + 3);
    }
    barrier_raw();
    __builtin_amdgcn_s_setprio(1);
    #pragma unroll
    for (int m = 0; m < 4; ++m)
      #pragma unroll
      for (int n = 0; n < 4; ++n)
        acc[m + 4][n] = __builtin_amdgcn_mfma_f32_16x16x32_bf16(af[m], bf[n], acc[m + 4][n], 0, 0, 0);
    __builtin_amdgcn_s_setprio(0);
    // once per K-tile: ensure tile T+1 landed before next iteration's reads
    if (T + 3 < NT)      { asm volatile("s_waitcnt vmcnt(8)" ::: "memory"); }
    else if (T + 2 < NT) { asm volatile("s_waitcnt vmcnt(4)" ::: "memory"); }
    else if (T + 1 < NT) { asm volatile("s_waitcnt vmcnt(0)" ::: "memory"); }
    barrier_raw();
  }

  // ---- epilogue: bias + decay scale folded, bf16 store ----
  // seg uniform per block: nt 0-2 = q, 3-5 = k, 6-8 = v  (768 = 3*256)
  const int lr = (lane >> 4) * 4;
  const int lc = lane & 15;
  const float L2A = -0.014499570f;     // log2(0.99)
  const float ISD = 0.03608439182f;    // 1/sqrt(768)
  const int seg = nt / 3;
  float bv[4];
  #pragma unroll
  for (int n = 0; n < 4; ++n)
    bv[n] = bias[nt * 256 + wn * 64 + n * 16 + lc];
  #pragma unroll
  for (int m = 0; m < 8; ++m) {
    #pragma unroll
    for (int j = 0; j < 4; ++j) {
      const int grow = mt * 256 + wm * 128 + m * 16 + lr + j;
      const int s = grow & (SEQ - 1);
      const float scale = (seg == 0) ? exp2f((float)s * L2A) * ISD
                        : (seg == 1) ? exp2f(-(float)s * L2A)
                                     : 1.0f;
      #pragma unroll
      for (int n = 0; n < 4; ++n) {
        const int gcol = nt * 256 + wn * 64 + n * 16 + lc;
        const float v = (acc[m][n][j] + bv[n]) * scale;
        qkv[(size_t)grow * NQKV + gcol] = f2bf(v);
      }
    }
  }
}

// ---------------------------------------------------------------------------
// gemm_bt core (128x128, 2-phase) — still used by qk / pv this round.
// ---------------------------------------------------------------------------
static __device__ __forceinline__ void gemm_bt_core(
    const u16* __restrict__ Ab, int lda,
    const u16* __restrict__ Bb, int ldb,
    int KT, u16* As, u16* Bs, f32x4 (&acc)[4][4])
{
  const int tid  = threadIdx.x;
  const int wid  = tid >> 6;
  const int lane = tid & 63;
  const int wrow = (wid >> 1) * 64;
  const int wcol = (wid & 1) * 64;

  #pragma unroll
  for (int m = 0; m < 4; ++m)
    #pragma unroll
    for (int n = 0; n < 4; ++n)
      acc[m][n] = (f32x4){0.f, 0.f, 0.f, 0.f};

  const int srow = tid >> 2;        // 0..63
  const int scol = (tid & 3) * 8;   // 0,8,16,24

  auto stage = [&](const u16* gb, int ld, u16* lds, int buf, int k0) {
    #pragma unroll
    for (int i = 0; i < 2; ++i) {
      const void* g = (const void*)(gb + (size_t)(i * 64 + srow) * ld + (k0 + scol));
      void* l = (void*)((char*)lds + buf * 8192 + i * 4096 + wid * 1024);
      gload_lds16(g, l);
    }
  };

  auto compute = [&](int buf) {
    const u16* a_ = As + buf * 4096;
    const u16* b_ = Bs + buf * 4096;
    short8 afr[4], bfr[4];
    const int ro = (lane & 15) * 32 + (lane >> 4) * 8;
    #pragma unroll
    for (int m = 0; m < 4; ++m)
      afr[m] = *(const short8*)(a_ + (wrow + m * 16) * 32 + ro);
    #pragma unroll
    for (int n = 0; n < 4; ++n)
      bfr[n] = *(const short8*)(b_ + (wcol + n * 16) * 32 + ro);
    #pragma unroll
    for (int m = 0; m < 4; ++m)
      #pragma unroll
      for (int n = 0; n < 4; ++n)
        acc[m][n] = __builtin_amdgcn_mfma_f32_16x16x32_bf16(afr[m], bfr[n], acc[m][n], 0, 0, 0);
  };

  stage(Ab, lda, As, 0, 0);
  stage(Bb, ldb, Bs, 0, 0);
  asm volatile("s_waitcnt vmcnt(0)" ::: "memory");
  __syncthreads();
  int cur = 0;
  for (int kt = 0; kt < KT; ++kt) {
    if (kt + 1 < KT) {
      stage(Ab, lda, As, cur ^ 1, (kt + 1) * 32);
      stage(Bb, ldb, Bs, cur ^ 1, (kt + 1) * 32);
    }
    compute(cur);
    asm volatile("s_waitcnt vmcnt(0)" ::: "memory");
    __syncthreads();
    cur ^= 1;
  }
}

// ---------------------------------------------------------------------------
// x fp32 -> bf16
__global__ __launch_bounds__(256)
void cvt_x_kernel(const float* __restrict__ X, u16* __restrict__ Xb) {
  const size_t i = ((size_t)blockIdx.x * 256 + threadIdx.x) * 8;
  f32x4 a = *(const f32x4*)(X + i);
  f32x4 b = *(const f32x4*)(X + i + 4);
  short8 r;
  #pragma unroll
  for (int j = 0; j < 4; ++j) { r[j] = (short)f2bf(a[j]); r[j + 4] = (short)f2bf(b[j]); }
  *(short8*)(Xb + i) = r;
}

// W [768][2304] fp32 -> Wt [2304][768] bf16
__global__ void wt_kernel(const float* __restrict__ W, u16* __restrict__ Wt) {
  __shared__ u16 t[32][33];
  const int n0 = blockIdx.x * 32, k0 = blockIdx.y * 32;
  const int tx = threadIdx.x, ty = threadIdx.y;
  #pragma unroll
  for (int r = 0; r < 4; ++r)
    t[ty + r * 8][tx] = f2bf(W[(size_t)(k0 + ty + r * 8) * NQKV + n0 + tx]);
  __syncthreads();
  #pragma unroll
  for (int r = 0; r < 4; ++r)
    Wt[(size_t)(n0 + ty + r * 8) * DIM + k0 + tx] = t[tx][ty + r * 8];
}

// v (inside qkv, col offset 1536) -> vT [b][d][t] bf16
__global__ void vt_kernel(const u16* __restrict__ qkv, u16* __restrict__ vT) {
  __shared__ u16 t[32][33];
  const int b = blockIdx.z;
  const int t0 = blockIdx.y * 32, d0 = blockIdx.x * 32;
  const int tx = threadIdx.x, ty = threadIdx.y;
  const u16* src = qkv + (size_t)b * SEQ * NQKV + 2 * DIM;
  #pragma unroll
  for (int r = 0; r < 4; ++r)
    t[ty + r * 8][tx] = src[(size_t)(t0 + ty + r * 8) * NQKV + d0 + tx];
  __syncthreads();
  u16* dst = vT + (size_t)b * DIM * SEQ;
  #pragma unroll
  for (int r = 0; r < 4; ++r)
    dst[(size_t)(d0 + ty + r * 8) * SEQ + t0 + tx] = t[tx][ty + r * 8];
}

// S = q~ @ k~^T per batch, lower-triangular tiles only; strict-upper zeroed
__global__ __launch_bounds__(256)
void qk_gemm_kernel(const u16* __restrict__ qkv, u16* __restrict__ S) {
  __shared__ u16 As[2 * 4096];
  __shared__ u16 Bs[2 * 4096];
  f32x4 acc[4][4];
  const int b = blockIdx.y;
  const int p = blockIdx.x;        // 0..35 triangular pair
  int it = 0;
  while ((it + 1) * (it + 2) / 2 <= p) ++it;
  const int jt = p - it * (it + 1) / 2;
  const u16* Ab = qkv + (size_t)(b * SEQ + it * 128) * NQKV;        // q rows
  const u16* Bb = qkv + (size_t)(b * SEQ + jt * 128) * NQKV + DIM;  // k rows
  gemm_bt_core(Ab, NQKV, Bb, NQKV, DIM / 32, As, Bs, acc);

  u16* Sb = S + (size_t)b * SEQ * SEQ;
  const int tid = threadIdx.x, wid = tid >> 6, lane = tid & 63;
  const int wrow = (wid >> 1) * 64, wcol = (wid & 1) * 64;
  const int lr = (lane >> 4) * 4, lc = lane & 15;
  #pragma unroll
  for (int m = 0; m < 4; ++m) {
    #pragma unroll
    for (int n = 0; n < 4; ++n) {
      const int c = jt * 128 + wcol + n * 16 + lc;
      #pragma unroll
      for (int j = 0; j < 4; ++j) {
        const int r = it * 128 + wrow + m * 16 + lr + j;
        float v = acc[m][n][j];
        if (c > r) v = 0.f;   // strict upper (only on diagonal tiles)
        Sb[(size_t)r * SEQ + c] = f2bf(v);
      }
    }
  }
}

// out = S @ v per batch (K-loop stops at the causal boundary)
__global__ __launch_bounds__(256)
void pv_gemm_kernel(const u16* __restrict__ S, const u16* __restrict__ vT,
                    float* __restrict__ out) {
  __shared__ u16 As[2 * 4096];
  __shared__ u16 Bs[2 * 4096];
  f32x4 acc[4][4];
  const int b = blockIdx.z, it = blockIdx.y, nt = blockIdx.x;
  const u16* Ab = S + (size_t)b * SEQ * SEQ + (size_t)it * 128 * SEQ;
  const u16* Bb = vT + (size_t)b * DIM * SEQ + (size_t)nt * 128 * SEQ;
  gemm_bt_core(Ab, SEQ, Bb, SEQ, (it + 1) * 4, As, Bs, acc);

  float* Ob = out + (size_t)b * SEQ * DIM;
  const int tid = threadIdx.x, wid = tid >> 6, lane = tid & 63;
  const int wrow = (wid >> 1) * 64, wcol = (wid & 1) * 64;
  const int lr = (lane >> 4) * 4, lc = lane & 15;
  #pragma unroll
  for (int m = 0; m < 4; ++m) {
    #pragma unroll
    for (int n = 0; n < 4; ++n) {
      const int c = nt * 128 + wcol + n * 16 + lc;
      #pragma unroll
      for (int j = 0; j < 4; ++j) {
        const int r = it * 128 + wrow + m * 16 + lr + j;
        Ob[(size_t)r * DIM + c] = acc[m][n][j];
      }
    }
  }
}

extern "C" void kernel_launch(void* const* d_in, const int* in_sizes, int n_in,
                              void* d_out, int out_size, void* d_ws, size_t ws_size,
                              hipStream_t stream) {
  const float* x    = (const float*)d_in[0];
  const float* W    = (const float*)d_in[1];
  const float* bias = (const float*)d_in[2];
  float* out = (float*)d_out;

  char* ws = (char*)d_ws;
  const size_t SZ_QKV = (size_t)BATCH * SEQ * NQKV * 2;  // 150,994,944
  const size_t SZ_WT  = (size_t)NQKV * DIM * 2;          //   3,538,944
  const size_t SZ_VT  = (size_t)BATCH * DIM * SEQ * 2;   //  50,331,648
  const size_t SZ_S   = (size_t)BATCH * SEQ * SEQ * 2;   //  67,108,864
  const size_t SZ_XB  = (size_t)BATCH * SEQ * DIM * 2;   //  50,331,648
  u16* qkv = (u16*)(ws);
  u16* Wt  = (u16*)(ws + SZ_QKV);
  u16* vT  = (u16*)(ws + SZ_QKV + SZ_WT);
  u16* Smt = (u16*)(ws + SZ_QKV + SZ_WT + SZ_VT);
  u16* Xb  = (u16*)(ws + SZ_QKV + SZ_WT + SZ_VT + SZ_S);
  if (ws_size < SZ_QKV + SZ_WT + SZ_VT + SZ_S + SZ_XB) return;  // need ~322MB

  (void)hipFuncSetAttribute((const void*)qkv256_kernel,
                            hipFuncAttributeMaxDynamicSharedMemorySize, 131072);

  cvt_x_kernel<<<dim3((BATCH * SEQ * DIM / 8) / 256), 256, 0, stream>>>(x, Xb);
  wt_kernel<<<dim3(NQKV / 32, DIM / 32), dim3(32, 8), 0, stream>>>(W, Wt);
  qkv256_kernel<<<dim3(1152), dim3(512), 131072, stream>>>(Xb, Wt, bias, qkv);
  vt_kernel<<<dim3(DIM / 32, SEQ / 32, BATCH), dim3(32, 8), 0, stream>>>(qkv, vT);
  qk_gemm_kernel<<<dim3(36, BATCH), 256, 0, stream>>>(qkv, Smt);
  pv_gemm_kernel<<<dim3(DIM / 128, SEQ / 128, BATCH), 256, 0, stream>>>(Smt, vT, out);
}

// Round 3
// 324.925 us; speedup vs baseline: 1.2550x; 1.1289x over previous
//
#include <hip/hip_runtime.h>
#include <stdint.h>

#define BATCH 32
#define SEQ   1024
#define DIM   768
#define NQKV  2304   // 3*DIM

typedef unsigned short u16;
typedef __attribute__((ext_vector_type(8))) short short8;   // 8 x bf16 (4 VGPRs)
typedef __attribute__((ext_vector_type(4))) float f32x4;
typedef __attribute__((ext_vector_type(4))) unsigned short us4;

// fp32 -> bf16 round-to-nearest-even (finite inputs)
static __device__ __forceinline__ u16 f2bf(float f) {
  uint32_t u = __float_as_uint(f);
  uint32_t r = (u + 0x7fffu + ((u >> 16) & 1u)) >> 16;
  return (u16)r;
}

static __device__ __forceinline__ void gload_lds16(const void* g, void* l) {
  __builtin_amdgcn_global_load_lds(
      (const __attribute__((address_space(1))) unsigned int*)g,
      (__attribute__((address_space(3))) unsigned int*)l, 16, 0, 0);
}

#define CFENCE asm volatile("" ::: "memory")
static __device__ __forceinline__ void barrier_raw() {
  CFENCE; __builtin_amdgcn_s_barrier(); CFENCE;
}

// ===========================================================================
// qkv GEMM: 256x256 tile, BK=32, ring-of-4 LDS K-tile buffers, 8 waves (2Mx4N).
// ONE barrier + ONE counted vmcnt per K-tile; no intra-tile barriers.
// Epilogue: q/k scaled+biased into qkv layout; v biased and written TRANSPOSED
// into vT[b][d][t] directly (nt 6..8 are pure-v blocks).
// ===========================================================================
__global__ __launch_bounds__(512, 2)
void qkv256_kernel(const u16* __restrict__ Xb, const u16* __restrict__ Wt,
                   const float* __restrict__ bias, u16* __restrict__ qkv,
                   u16* __restrict__ vT) {
  extern __shared__ char smem[];        // 131072 bytes
  char* smemA = smem;                    // 4 rings * 16384 B
  char* smemB = smem + 65536;            // 4 rings * 16384 B

  const int bid = blockIdx.x;
  const int swz = (bid & 7) * 144 + (bid >> 3);   // bijective, 1152 % 8 == 0
  const int mt = swz / 9;
  const int nt = swz % 9;

  const int tid  = threadIdx.x;
  const int wid  = tid >> 6;
  const int lane = tid & 63;
  const int wm   = wid >> 2;             // 0..1
  const int wn   = wid & 3;              // 0..3

  const u16* Ag = Xb + (size_t)mt * 256 * DIM;
  const u16* Bg = Wt + (size_t)nt * 256 * DIM;

  f32x4 acc[8][4];
  #pragma unroll
  for (int m = 0; m < 8; ++m)
    #pragma unroll
    for (int n = 0; n < 4; ++n)
      acc[m][n] = (f32x4){0.f, 0.f, 0.f, 0.f};

  auto stage = [&](const u16* gb, char* lsbase, int ring, int half, int kt) {
    const int doff = tid << 4;                                   // 0..8191
    const int loff = doff ^ (((doff >> 7) & 3) << 4);            // involution
    const int row  = loff >> 6;                                  // 0..127
    const int colb = loff & 63;
    const char* src = (const char*)gb +
        ((size_t)(half * 128 + row) * DIM + (size_t)kt * 32) * 2 + colb;
    char* dst = lsbase + ring * 16384 + half * 8192 + (wid << 10);  // wave-uniform
    gload_lds16(src, dst);
  };

  const int NT = DIM / 32;               // 24

  for (int t = 0; t < 3; ++t) {
    stage(Ag, smemA, t, 0, t); stage(Ag, smemA, t, 1, t);
    stage(Bg, smemB, t, 0, t); stage(Bg, smemB, t, 1, t);
  }
  asm volatile("s_waitcnt vmcnt(8)" ::: "memory");   // tile 0 landed
  barrier_raw();

  const int lrow = lane & 15;
  const int c0   = lane >> 4;

  for (int T = 0; T < NT; ++T) {
    const int ring = T & 3;
    if (T + 3 < NT) {
      const int r3 = (T + 3) & 3;
      stage(Ag, smemA, r3, 0, T + 3); stage(Ag, smemA, r3, 1, T + 3);
      stage(Bg, smemB, r3, 0, T + 3); stage(Bg, smemB, r3, 1, T + 3);
    }
    const char* abase = smemA + ring * 16384 + wm * 8192;
    const char* bbase = smemB + ring * 16384 + (wn >> 1) * 8192;
    short8 bf[4], af[8];
    #pragma unroll
    for (int n = 0; n < 4; ++n) {
      const int row = (wn & 1) * 64 + n * 16 + lrow;
      const int c = c0 ^ ((row >> 1) & 3);
      bf[n] = *(const short8*)(bbase + row * 64 + c * 16);
    }
    #pragma unroll
    for (int m = 0; m < 8; ++m) {
      const int row = m * 16 + lrow;
      const int c = c0 ^ ((row >> 1) & 3);
      af[m] = *(const short8*)(abase + row * 64 + c * 16);
    }
    __builtin_amdgcn_s_setprio(1);
    #pragma unroll
    for (int m = 0; m < 8; ++m)
      #pragma unroll
      for (int n = 0; n < 4; ++n)
        acc[m][n] = __builtin_amdgcn_mfma_f32_16x16x32_bf16(af[m], bf[n], acc[m][n], 0, 0, 0);
    __builtin_amdgcn_s_setprio(0);
    if (T + 3 < NT)      { asm volatile("s_waitcnt vmcnt(8)" ::: "memory"); }
    else if (T + 2 < NT) { asm volatile("s_waitcnt vmcnt(4)" ::: "memory"); }
    else if (T + 1 < NT) { asm volatile("s_waitcnt vmcnt(0)" ::: "memory"); }
    barrier_raw();
  }

  // ---- epilogue ----
  const int lr = (lane >> 4) * 4;
  const int lc = lane & 15;
  const float L2A = -0.014499570f;     // log2(0.99)
  const float ISD = 0.03608439182f;    // 1/sqrt(768)
  const int seg = nt / 3;              // uniform per block
  float bv[4];
  #pragma unroll
  for (int n = 0; n < 4; ++n)
    bv[n] = bias[nt * 256 + wn * 64 + n * 16 + lc];

  if (seg < 2) {
    #pragma unroll
    for (int m = 0; m < 8; ++m) {
      const int grow0 = mt * 256 + wm * 128 + m * 16 + lr;
      #pragma unroll
      for (int j = 0; j < 4; ++j) {
        const int s = (grow0 + j) & (SEQ - 1);
        const float scale = (seg == 0) ? exp2f((float)s * L2A) * ISD
                                       : exp2f(-(float)s * L2A);
        #pragma unroll
        for (int n = 0; n < 4; ++n) {
          const int gcol = nt * 256 + wn * 64 + n * 16 + lc;
          qkv[(size_t)(grow0 + j) * NQKV + gcol] = f2bf((acc[m][n][j] + bv[n]) * scale);
        }
      }
    }
  } else {
    // v block: write transposed into vT[b][d][t]; j = consecutive t -> us4
    #pragma unroll
    for (int m = 0; m < 8; ++m) {
      const int grow0 = mt * 256 + wm * 128 + m * 16 + lr;
      const int b  = grow0 >> 10;
      const int t0 = grow0 & (SEQ - 1);
      #pragma unroll
      for (int n = 0; n < 4; ++n) {
        const int d = (nt - 6) * 256 + wn * 64 + n * 16 + lc;
        us4 val;
        #pragma unroll
        for (int j = 0; j < 4; ++j) val[j] = f2bf(acc[m][n][j] + bv[n]);
        *(us4*)(vT + ((size_t)b * DIM + d) * SEQ + t0) = val;
      }
    }
  }
}

// ===========================================================================
// 128x128 ring-of-4 bt-GEMM core (4 waves, BK=32, 1 barrier/K-tile, 64KB LDS
// -> 2 blocks/CU). Used by qk and pv.
// ===========================================================================
static __device__ __forceinline__ void ring_core_128(
    const u16* __restrict__ Ab, int lda,
    const u16* __restrict__ Bb, int ldb,
    int KT, char* smemA, char* smemB, f32x4 (&acc)[4][4])
{
  const int tid  = threadIdx.x;
  const int wid  = tid >> 6;
  const int lane = tid & 63;
  const int wrow = (wid >> 1) * 64;
  const int wcol = (wid & 1) * 64;

  #pragma unroll
  for (int m = 0; m < 4; ++m)
    #pragma unroll
    for (int n = 0; n < 4; ++n)
      acc[m][n] = (f32x4){0.f, 0.f, 0.f, 0.f};

  auto stage = [&](const u16* gb, int ld, char* lsbase, int ring, int half, int kt) {
    const int doff = tid << 4;                          // 0..4095
    const int loff = doff ^ (((doff >> 7) & 3) << 4);   // involution on bits 4-5
    const int row  = half * 64 + (loff >> 6);           // 0..127
    const int colb = loff & 63;
    const char* src = (const char*)gb + ((size_t)row * ld + (size_t)kt * 32) * 2 + colb;
    char* dst = lsbase + ring * 8192 + half * 4096 + (wid << 10);  // wave-uniform
    gload_lds16(src, dst);
  };

  for (int t = 0; t < 3; ++t) {   // callers guarantee KT >= 4
    stage(Ab, lda, smemA, t, 0, t); stage(Ab, lda, smemA, t, 1, t);
    stage(Bb, ldb, smemB, t, 0, t); stage(Bb, ldb, smemB, t, 1, t);
  }
  asm volatile("s_waitcnt vmcnt(8)" ::: "memory");
  barrier_raw();

  const int lrow = lane & 15;
  const int c0   = lane >> 4;

  for (int T = 0; T < KT; ++T) {
    const int ring = T & 3;
    if (T + 3 < KT) {
      const int r3 = (T + 3) & 3;
      stage(Ab, lda, smemA, r3, 0, T + 3); stage(Ab, lda, smemA, r3, 1, T + 3);
      stage(Bb, ldb, smemB, r3, 0, T + 3); stage(Bb, ldb, smemB, r3, 1, T + 3);
    }
    const char* abase = smemA + ring * 8192;
    const char* bbase = smemB + ring * 8192;
    short8 af[4], bf[4];
    #pragma unroll
    for (int n = 0; n < 4; ++n) {
      const int row = wcol + n * 16 + lrow;
      const int c = c0 ^ ((row >> 1) & 3);
      bf[n] = *(const short8*)(bbase + row * 64 + c * 16);
    }
    #pragma unroll
    for (int m = 0; m < 4; ++m) {
      const int row = wrow + m * 16 + lrow;
      const int c = c0 ^ ((row >> 1) & 3);
      af[m] = *(const short8*)(abase + row * 64 + c * 16);
    }
    __builtin_amdgcn_s_setprio(1);
    #pragma unroll
    for (int m = 0; m < 4; ++m)
      #pragma unroll
      for (int n = 0; n < 4; ++n)
        acc[m][n] = __builtin_amdgcn_mfma_f32_16x16x32_bf16(af[m], bf[n], acc[m][n], 0, 0, 0);
    __builtin_amdgcn_s_setprio(0);
    if (T + 3 < KT)      { asm volatile("s_waitcnt vmcnt(8)" ::: "memory"); }
    else if (T + 2 < KT) { asm volatile("s_waitcnt vmcnt(4)" ::: "memory"); }
    else if (T + 1 < KT) { asm volatile("s_waitcnt vmcnt(0)" ::: "memory"); }
    barrier_raw();
  }
}

// ---------------------------------------------------------------------------
// x fp32 -> bf16
__global__ __launch_bounds__(256)
void cvt_x_kernel(const float* __restrict__ X, u16* __restrict__ Xb) {
  const size_t i = ((size_t)blockIdx.x * 256 + threadIdx.x) * 8;
  f32x4 a = *(const f32x4*)(X + i);
  f32x4 b = *(const f32x4*)(X + i + 4);
  short8 r;
  #pragma unroll
  for (int j = 0; j < 4; ++j) { r[j] = (short)f2bf(a[j]); r[j + 4] = (short)f2bf(b[j]); }
  *(short8*)(Xb + i) = r;
}

// W [768][2304] fp32 -> Wt [2304][768] bf16
__global__ void wt_kernel(const float* __restrict__ W, u16* __restrict__ Wt) {
  __shared__ u16 t[32][33];
  const int n0 = blockIdx.x * 32, k0 = blockIdx.y * 32;
  const int tx = threadIdx.x, ty = threadIdx.y;
  #pragma unroll
  for (int r = 0; r < 4; ++r)
    t[ty + r * 8][tx] = f2bf(W[(size_t)(k0 + ty + r * 8) * NQKV + n0 + tx]);
  __syncthreads();
  #pragma unroll
  for (int r = 0; r < 4; ++r)
    Wt[(size_t)(n0 + ty + r * 8) * DIM + k0 + tx] = t[tx][ty + r * 8];
}

// S = q~ @ k~^T per batch, lower-triangular tiles only; strict-upper zeroed
__global__ __launch_bounds__(256, 2)
void qk_gemm_kernel(const u16* __restrict__ qkv, u16* __restrict__ S) {
  extern __shared__ char smem[];      // 65536
  f32x4 acc[4][4];
  const int b = blockIdx.y;
  const int p = blockIdx.x;           // 0..35 triangular pair
  int it = 0;
  while ((it + 1) * (it + 2) / 2 <= p) ++it;
  const int jt = p - it * (it + 1) / 2;
  const u16* Ab = qkv + (size_t)(b * SEQ + it * 128) * NQKV;        // q rows
  const u16* Bb = qkv + (size_t)(b * SEQ + jt * 128) * NQKV + DIM;  // k rows
  ring_core_128(Ab, NQKV, Bb, NQKV, DIM / 32, smem, smem + 32768, acc);

  u16* Sb = S + (size_t)b * SEQ * SEQ;
  const int tid = threadIdx.x, wid = tid >> 6, lane = tid & 63;
  const int wrow = (wid >> 1) * 64, wcol = (wid & 1) * 64;
  const int lr = (lane >> 4) * 4, lc = lane & 15;
  #pragma unroll
  for (int m = 0; m < 4; ++m) {
    #pragma unroll
    for (int n = 0; n < 4; ++n) {
      const int c = jt * 128 + wcol + n * 16 + lc;
      #pragma unroll
      for (int j = 0; j < 4; ++j) {
        const int r = it * 128 + wrow + m * 16 + lr + j;
        float v = acc[m][n][j];
        if (c > r) v = 0.f;   // strict upper (only on diagonal tiles)
        Sb[(size_t)r * SEQ + c] = f2bf(v);
      }
    }
  }
}

// out = S @ v per batch (K-loop stops at the causal boundary)
__global__ __launch_bounds__(256, 2)
void pv_gemm_kernel(const u16* __restrict__ S, const u16* __restrict__ vT,
                    float* __restrict__ out) {
  extern __shared__ char smem[];      // 65536
  f32x4 acc[4][4];
  const int b = blockIdx.z, it = blockIdx.y, nt = blockIdx.x;
  const u16* Ab = S + (size_t)b * SEQ * SEQ + (size_t)it * 128 * SEQ;
  const u16* Bb = vT + (size_t)b * DIM * SEQ + (size_t)nt * 128 * SEQ;
  ring_core_128(Ab, SEQ, Bb, SEQ, (it + 1) * 4, smem, smem + 32768, acc);

  float* Ob = out + (size_t)b * SEQ * DIM;
  const int tid = threadIdx.x, wid = tid >> 6, lane = tid & 63;
  const int wrow = (wid >> 1) * 64, wcol = (wid & 1) * 64;
  const int lr = (lane >> 4) * 4, lc = lane & 15;
  #pragma unroll
  for (int m = 0; m < 4; ++m) {
    #pragma unroll
    for (int n = 0; n < 4; ++n) {
      const int c = nt * 128 + wcol + n * 16 + lc;
      #pragma unroll
      for (int j = 0; j < 4; ++j) {
        const int r = it * 128 + wrow + m * 16 + lr + j;
        Ob[(size_t)r * DIM + c] = acc[m][n][j];
      }
    }
  }
}

extern "C" void kernel_launch(void* const* d_in, const int* in_sizes, int n_in,
                              void* d_out, int out_size, void* d_ws, size_t ws_size,
                              hipStream_t stream) {
  const float* x    = (const float*)d_in[0];
  const float* W    = (const float*)d_in[1];
  const float* bias = (const float*)d_in[2];
  float* out = (float*)d_out;

  char* ws = (char*)d_ws;
  const size_t SZ_QKV = (size_t)BATCH * SEQ * NQKV * 2;  // 150,994,944
  const size_t SZ_WT  = (size_t)NQKV * DIM * 2;          //   3,538,944
  const size_t SZ_VT  = (size_t)BATCH * DIM * SEQ * 2;   //  50,331,648
  const size_t SZ_S   = (size_t)BATCH * SEQ * SEQ * 2;   //  67,108,864
  const size_t SZ_XB  = (size_t)BATCH * SEQ * DIM * 2;   //  50,331,648
  u16* qkv = (u16*)(ws);
  u16* Wt  = (u16*)(ws + SZ_QKV);
  u16* vT  = (u16*)(ws + SZ_QKV + SZ_WT);
  u16* Smt = (u16*)(ws + SZ_QKV + SZ_WT + SZ_VT);
  u16* Xb  = (u16*)(ws + SZ_QKV + SZ_WT + SZ_VT + SZ_S);
  if (ws_size < SZ_QKV + SZ_WT + SZ_VT + SZ_S + SZ_XB) return;  // need ~322MB

  (void)hipFuncSetAttribute((const void*)qkv256_kernel,
                            hipFuncAttributeMaxDynamicSharedMemorySize, 131072);
  (void)hipFuncSetAttribute((const void*)qk_gemm_kernel,
                            hipFuncAttributeMaxDynamicSharedMemorySize, 65536);
  (void)hipFuncSetAttribute((const void*)pv_gemm_kernel,
                            hipFuncAttributeMaxDynamicSharedMemorySize, 65536);

  cvt_x_kernel<<<dim3((BATCH * SEQ * DIM / 8) / 256), 256, 0, stream>>>(x, Xb);
  wt_kernel<<<dim3(NQKV / 32, DIM / 32), dim3(32, 8), 0, stream>>>(W, Wt);
  qkv256_kernel<<<dim3(1152), dim3(512), 131072, stream>>>(Xb, Wt, bias, qkv, vT);
  qk_gemm_kernel<<<dim3(36, BATCH), 256, 65536, stream>>>(qkv, Smt);
  pv_gemm_kernel<<<dim3(DIM / 128, SEQ / 128, BATCH), 256, 65536, stream>>>(Smt, vT, out);
}

// Round 4
// 317.075 us; speedup vs baseline: 1.2861x; 1.0248x over previous
//
#include <hip/hip_runtime.h>
#include <stdint.h>

#define BATCH 32
#define SEQ   1024
#define DIM   768
#define NQKV  2304   // 3*DIM

typedef unsigned short u16;
typedef __attribute__((ext_vector_type(8))) short short8;   // 8 x bf16 (4 VGPRs)
typedef __attribute__((ext_vector_type(4))) float f32x4;
typedef __attribute__((ext_vector_type(4))) unsigned short us4;

// fp32 -> bf16 round-to-nearest-even (finite inputs)
static __device__ __forceinline__ u16 f2bf(float f) {
  uint32_t u = __float_as_uint(f);
  uint32_t r = (u + 0x7fffu + ((u >> 16) & 1u)) >> 16;
  return (u16)r;
}

static __device__ __forceinline__ void gload_lds16(const void* g, void* l) {
  __builtin_amdgcn_global_load_lds(
      (const __attribute__((address_space(1))) unsigned int*)g,
      (__attribute__((address_space(3))) unsigned int*)l, 16, 0, 0);
}

#define CFENCE asm volatile("" ::: "memory")
static __device__ __forceinline__ void barrier_raw() {
  CFENCE; __builtin_amdgcn_s_barrier(); CFENCE;
}

// ===========================================================================
// qkv GEMM: 256x256 tile, BK=32, ring-of-4 LDS buffers, 8 waves (2Mx4N).
// Software-pipelined: tile T+1's ds_reads are issued into the alternate frag
// register buffer WHILE tile T's MFMAs run. One counted vmcnt + one raw
// barrier per K-tile, at the END of the iteration.
// Invariant at iter-T start: tile T+1's global_load_lds landed on all waves.
// ===========================================================================
__global__ __launch_bounds__(512, 2)
void qkv256_kernel(const u16* __restrict__ Xb, const u16* __restrict__ Wt,
                   const float* __restrict__ bias, u16* __restrict__ qkv,
                   u16* __restrict__ vT) {
  extern __shared__ char smem[];        // 131072 bytes
  char* smemA = smem;                    // 4 rings * 16384 B
  char* smemB = smem + 65536;            // 4 rings * 16384 B

  const int bid = blockIdx.x;
  const int swz = (bid & 7) * 144 + (bid >> 3);   // bijective, 1152 % 8 == 0
  const int mt = swz / 9;
  const int nt = swz % 9;

  const int tid  = threadIdx.x;
  const int wid  = tid >> 6;
  const int lane = tid & 63;
  const int wm   = wid >> 2;             // 0..1
  const int wn   = wid & 3;              // 0..3

  const u16* Ag = Xb + (size_t)mt * 256 * DIM;
  const u16* Bg = Wt + (size_t)nt * 256 * DIM;

  f32x4 acc[8][4];
  #pragma unroll
  for (int m = 0; m < 8; ++m)
    #pragma unroll
    for (int n = 0; n < 4; ++n)
      acc[m][n] = (f32x4){0.f, 0.f, 0.f, 0.f};

  auto stage = [&](const u16* gb, char* lsbase, int ring, int half, int kt) {
    const int doff = tid << 4;                                   // 0..8191
    const int loff = doff ^ (((doff >> 7) & 3) << 4);            // involution
    const int row  = loff >> 6;                                  // 0..127
    const int colb = loff & 63;
    const char* src = (const char*)gb +
        ((size_t)(half * 128 + row) * DIM + (size_t)kt * 32) * 2 + colb;
    char* dst = lsbase + ring * 16384 + half * 8192 + (wid << 10);  // wave-uniform
    gload_lds16(src, dst);
  };
  auto stage_tile = [&](int kt) {
    const int r = kt & 3;
    stage(Ag, smemA, r, 0, kt); stage(Ag, smemA, r, 1, kt);
    stage(Bg, smemB, r, 0, kt); stage(Bg, smemB, r, 1, kt);
  };

  const int lrow = lane & 15;
  const int c0   = lane >> 4;

  auto read_frags = [&](int kt, short8 (&af)[8], short8 (&bf)[4]) {
    const int ring = kt & 3;
    const char* abase = smemA + ring * 16384 + wm * 8192;
    const char* bbase = smemB + ring * 16384 + (wn >> 1) * 8192;
    #pragma unroll
    for (int n = 0; n < 4; ++n) {
      const int row = (wn & 1) * 64 + n * 16 + lrow;
      const int c = c0 ^ ((row >> 1) & 3);
      bf[n] = *(const short8*)(bbase + row * 64 + c * 16);
    }
    #pragma unroll
    for (int m = 0; m < 8; ++m) {
      const int row = m * 16 + lrow;
      const int c = c0 ^ ((row >> 1) & 3);
      af[m] = *(const short8*)(abase + row * 64 + c * 16);
    }
  };
  auto mfma_tile = [&](short8 (&af)[8], short8 (&bf)[4]) {
    __builtin_amdgcn_s_setprio(1);
    #pragma unroll
    for (int m = 0; m < 8; ++m)
      #pragma unroll
      for (int n = 0; n < 4; ++n)
        acc[m][n] = __builtin_amdgcn_mfma_f32_16x16x32_bf16(af[m], bf[n], acc[m][n], 0, 0, 0);
    __builtin_amdgcn_s_setprio(0);
    __builtin_amdgcn_sched_barrier(0);   // pin MFMAs before end-of-iter waits
  };

  const int NT = DIM / 32;               // 24 (even)

  short8 afA[8], bfA[4], afB[8], bfB[4];

  // prologue: stage tiles 0..2; land 0 AND 1; read tile 0 into buffer A
  stage_tile(0); stage_tile(1); stage_tile(2);
  asm volatile("s_waitcnt vmcnt(4)" ::: "memory");
  barrier_raw();
  read_frags(0, afA, bfA);

  for (int T = 0; T < NT; T += 2) {
    // even iter: consume A (tile T), fill B (tile T+1)
    if (T + 3 < NT) stage_tile(T + 3);
    if (T + 1 < NT) read_frags(T + 1, afB, bfB);
    mfma_tile(afA, bfA);
    if (T + 2 < NT) {
      if (T + 3 < NT) { asm volatile("s_waitcnt vmcnt(4)" ::: "memory"); }
      else            { asm volatile("s_waitcnt vmcnt(0)" ::: "memory"); }
      barrier_raw();
    }
    // odd iter U=T+1: consume B (tile U), fill A (tile U+1)
    const int U = T + 1;
    if (U + 3 < NT) stage_tile(U + 3);
    if (U + 1 < NT) read_frags(U + 1, afA, bfA);
    mfma_tile(afB, bfB);
    if (U + 2 < NT) {
      if (U + 3 < NT) { asm volatile("s_waitcnt vmcnt(4)" ::: "memory"); }
      else            { asm volatile("s_waitcnt vmcnt(0)" ::: "memory"); }
      barrier_raw();
    }
  }

  // ---- epilogue ----
  const int lr = (lane >> 4) * 4;
  const int lc = lane & 15;
  const float L2A = -0.014499570f;     // log2(0.99)
  const float ISD = 0.03608439182f;    // 1/sqrt(768)
  const int seg = nt / 3;              // uniform per block
  float bv[4];
  #pragma unroll
  for (int n = 0; n < 4; ++n)
    bv[n] = bias[nt * 256 + wn * 64 + n * 16 + lc];

  if (seg < 2) {
    #pragma unroll
    for (int m = 0; m < 8; ++m) {
      const int grow0 = mt * 256 + wm * 128 + m * 16 + lr;
      #pragma unroll
      for (int j = 0; j < 4; ++j) {
        const int s = (grow0 + j) & (SEQ - 1);
        const float scale = (seg == 0) ? exp2f((float)s * L2A) * ISD
                                       : exp2f(-(float)s * L2A);
        #pragma unroll
        for (int n = 0; n < 4; ++n) {
          const int gcol = nt * 256 + wn * 64 + n * 16 + lc;
          qkv[(size_t)(grow0 + j) * NQKV + gcol] = f2bf((acc[m][n][j] + bv[n]) * scale);
        }
      }
    }
  } else {
    // v block: write transposed into vT[b][d][t]; j = consecutive t -> us4
    #pragma unroll
    for (int m = 0; m < 8; ++m) {
      const int grow0 = mt * 256 + wm * 128 + m * 16 + lr;
      const int b  = grow0 >> 10;
      const int t0 = grow0 & (SEQ - 1);
      #pragma unroll
      for (int n = 0; n < 4; ++n) {
        const int d = (nt - 6) * 256 + wn * 64 + n * 16 + lc;
        us4 val;
        #pragma unroll
        for (int j = 0; j < 4; ++j) val[j] = f2bf(acc[m][n][j] + bv[n]);
        *(us4*)(vT + ((size_t)b * DIM + d) * SEQ + t0) = val;
      }
    }
  }
}

// ===========================================================================
// 128x128 pipelined ring-of-4 bt-GEMM core (4 waves, BK=32, 64KB LDS ->
// 2 blocks/CU). Same software-pipeline structure as qkv256. KT even, >= 4.
// ===========================================================================
static __device__ __forceinline__ void ring_core_128(
    const u16* __restrict__ Ab, int lda,
    const u16* __restrict__ Bb, int ldb,
    int KT, char* smemA, char* smemB, f32x4 (&acc)[4][4])
{
  const int tid  = threadIdx.x;
  const int wid  = tid >> 6;
  const int lane = tid & 63;
  const int wrow = (wid >> 1) * 64;
  const int wcol = (wid & 1) * 64;

  #pragma unroll
  for (int m = 0; m < 4; ++m)
    #pragma unroll
    for (int n = 0; n < 4; ++n)
      acc[m][n] = (f32x4){0.f, 0.f, 0.f, 0.f};

  auto stage = [&](const u16* gb, int ld, char* lsbase, int ring, int half, int kt) {
    const int doff = tid << 4;                          // 0..4095
    const int loff = doff ^ (((doff >> 7) & 3) << 4);   // involution on bits 4-5
    const int row  = half * 64 + (loff >> 6);           // 0..127
    const int colb = loff & 63;
    const char* src = (const char*)gb + ((size_t)row * ld + (size_t)kt * 32) * 2 + colb;
    char* dst = lsbase + ring * 8192 + half * 4096 + (wid << 10);  // wave-uniform
    gload_lds16(src, dst);
  };
  auto stage_tile = [&](int kt) {
    const int r = kt & 3;
    stage(Ab, lda, smemA, r, 0, kt); stage(Ab, lda, smemA, r, 1, kt);
    stage(Bb, ldb, smemB, r, 0, kt); stage(Bb, ldb, smemB, r, 1, kt);
  };

  const int lrow = lane & 15;
  const int c0   = lane >> 4;

  auto read_frags = [&](int kt, short8 (&af)[4], short8 (&bf)[4]) {
    const char* abase = smemA + (kt & 3) * 8192;
    const char* bbase = smemB + (kt & 3) * 8192;
    #pragma unroll
    for (int n = 0; n < 4; ++n) {
      const int row = wcol + n * 16 + lrow;
      const int c = c0 ^ ((row >> 1) & 3);
      bf[n] = *(const short8*)(bbase + row * 64 + c * 16);
    }
    #pragma unroll
    for (int m = 0; m < 4; ++m) {
      const int row = wrow + m * 16 + lrow;
      const int c = c0 ^ ((row >> 1) & 3);
      af[m] = *(const short8*)(abase + row * 64 + c * 16);
    }
  };
  auto mfma_tile = [&](short8 (&af)[4], short8 (&bf)[4]) {
    __builtin_amdgcn_s_setprio(1);
    #pragma unroll
    for (int m = 0; m < 4; ++m)
      #pragma unroll
      for (int n = 0; n < 4; ++n)
        acc[m][n] = __builtin_amdgcn_mfma_f32_16x16x32_bf16(af[m], bf[n], acc[m][n], 0, 0, 0);
    __builtin_amdgcn_s_setprio(0);
    __builtin_amdgcn_sched_barrier(0);
  };

  short8 afA[4], bfA[4], afB[4], bfB[4];

  stage_tile(0); stage_tile(1); stage_tile(2);
  asm volatile("s_waitcnt vmcnt(4)" ::: "memory");
  barrier_raw();
  read_frags(0, afA, bfA);

  for (int T = 0; T < KT; T += 2) {
    if (T + 3 < KT) stage_tile(T + 3);
    if (T + 1 < KT) read_frags(T + 1, afB, bfB);
    mfma_tile(afA, bfA);
    if (T + 2 < KT) {
      if (T + 3 < KT) { asm volatile("s_waitcnt vmcnt(4)" ::: "memory"); }
      else            { asm volatile("s_waitcnt vmcnt(0)" ::: "memory"); }
      barrier_raw();
    }
    const int U = T + 1;
    if (U + 3 < KT) stage_tile(U + 3);
    if (U + 1 < KT) read_frags(U + 1, afA, bfA);
    mfma_tile(afB, bfB);
    if (U + 2 < KT) {
      if (U + 3 < KT) { asm volatile("s_waitcnt vmcnt(4)" ::: "memory"); }
      else            { asm volatile("s_waitcnt vmcnt(0)" ::: "memory"); }
      barrier_raw();
    }
  }
}

// ---------------------------------------------------------------------------
// x fp32 -> bf16
__global__ __launch_bounds__(256)
void cvt_x_kernel(const float* __restrict__ X, u16* __restrict__ Xb) {
  const size_t i = ((size_t)blockIdx.x * 256 + threadIdx.x) * 8;
  f32x4 a = *(const f32x4*)(X + i);
  f32x4 b = *(const f32x4*)(X + i + 4);
  short8 r;
  #pragma unroll
  for (int j = 0; j < 4; ++j) { r[j] = (short)f2bf(a[j]); r[j + 4] = (short)f2bf(b[j]); }
  *(short8*)(Xb + i) = r;
}

// W [768][2304] fp32 -> Wt [2304][768] bf16
__global__ void wt_kernel(const float* __restrict__ W, u16* __restrict__ Wt) {
  __shared__ u16 t[32][33];
  const int n0 = blockIdx.x * 32, k0 = blockIdx.y * 32;
  const int tx = threadIdx.x, ty = threadIdx.y;
  #pragma unroll
  for (int r = 0; r < 4; ++r)
    t[ty + r * 8][tx] = f2bf(W[(size_t)(k0 + ty + r * 8) * NQKV + n0 + tx]);
  __syncthreads();
  #pragma unroll
  for (int r = 0; r < 4; ++r)
    Wt[(size_t)(n0 + ty + r * 8) * DIM + k0 + tx] = t[tx][ty + r * 8];
}

// S = q~ @ k~^T per batch, lower-triangular tiles only; strict-upper zeroed
__global__ __launch_bounds__(256, 2)
void qk_gemm_kernel(const u16* __restrict__ qkv, u16* __restrict__ S) {
  extern __shared__ char smem[];      // 65536
  f32x4 acc[4][4];
  const int b = blockIdx.y;
  const int p = blockIdx.x;           // 0..35 triangular pair
  int it = 0;
  while ((it + 1) * (it + 2) / 2 <= p) ++it;
  const int jt = p - it * (it + 1) / 2;
  const u16* Ab = qkv + (size_t)(b * SEQ + it * 128) * NQKV;        // q rows
  const u16* Bb = qkv + (size_t)(b * SEQ + jt * 128) * NQKV + DIM;  // k rows
  ring_core_128(Ab, NQKV, Bb, NQKV, DIM / 32, smem, smem + 32768, acc);

  u16* Sb = S + (size_t)b * SEQ * SEQ;
  const int tid = threadIdx.x, wid = tid >> 6, lane = tid & 63;
  const int wrow = (wid >> 1) * 64, wcol = (wid & 1) * 64;
  const int lr = (lane >> 4) * 4, lc = lane & 15;
  #pragma unroll
  for (int m = 0; m < 4; ++m) {
    #pragma unroll
    for (int n = 0; n < 4; ++n) {
      const int c = jt * 128 + wcol + n * 16 + lc;
      #pragma unroll
      for (int j = 0; j < 4; ++j) {
        const int r = it * 128 + wrow + m * 16 + lr + j;
        float v = acc[m][n][j];
        if (c > r) v = 0.f;   // strict upper (only on diagonal tiles)
        Sb[(size_t)r * SEQ + c] = f2bf(v);
      }
    }
  }
}

// out = S @ v per batch (K-loop stops at the causal boundary)
__global__ __launch_bounds__(256, 2)
void pv_gemm_kernel(const u16* __restrict__ S, const u16* __restrict__ vT,
                    float* __restrict__ out) {
  extern __shared__ char smem[];      // 65536
  f32x4 acc[4][4];
  const int b = blockIdx.z, it = blockIdx.y, nt = blockIdx.x;
  const u16* Ab = S + (size_t)b * SEQ * SEQ + (size_t)it * 128 * SEQ;
  const u16* Bb = vT + (size_t)b * DIM * SEQ + (size_t)nt * 128 * SEQ;
  ring_core_128(Ab, SEQ, Bb, SEQ, (it + 1) * 4, smem, smem + 32768, acc);

  float* Ob = out + (size_t)b * SEQ * DIM;
  const int tid = threadIdx.x, wid = tid >> 6, lane = tid & 63;
  const int wrow = (wid >> 1) * 64, wcol = (wid & 1) * 64;
  const int lr = (lane >> 4) * 4, lc = lane & 15;
  #pragma unroll
  for (int m = 0; m < 4; ++m) {
    #pragma unroll
    for (int n = 0; n < 4; ++n) {
      const int c = nt * 128 + wcol + n * 16 + lc;
      #pragma unroll
      for (int j = 0; j < 4; ++j) {
        const int r = it * 128 + wrow + m * 16 + lr + j;
        Ob[(size_t)r * DIM + c] = acc[m][n][j];
      }
    }
  }
}

extern "C" void kernel_launch(void* const* d_in, const int* in_sizes, int n_in,
                              void* d_out, int out_size, void* d_ws, size_t ws_size,
                              hipStream_t stream) {
  const float* x    = (const float*)d_in[0];
  const float* W    = (const float*)d_in[1];
  const float* bias = (const float*)d_in[2];
  float* out = (float*)d_out;

  char* ws = (char*)d_ws;
  const size_t SZ_QKV = (size_t)BATCH * SEQ * NQKV * 2;  // 150,994,944
  const size_t SZ_WT  = (size_t)NQKV * DIM * 2;          //   3,538,944
  const size_t SZ_VT  = (size_t)BATCH * DIM * SEQ * 2;   //  50,331,648
  const size_t SZ_S   = (size_t)BATCH * SEQ * SEQ * 2;   //  67,108,864
  const size_t SZ_XB  = (size_t)BATCH * SEQ * DIM * 2;   //  50,331,648
  u16* qkv = (u16*)(ws);
  u16* Wt  = (u16*)(ws + SZ_QKV);
  u16* vT  = (u16*)(ws + SZ_QKV + SZ_WT);
  u16* Smt = (u16*)(ws + SZ_QKV + SZ_WT + SZ_VT);
  u16* Xb  = (u16*)(ws + SZ_QKV + SZ_WT + SZ_VT + SZ_S);
  if (ws_size < SZ_QKV + SZ_WT + SZ_VT + SZ_S + SZ_XB) return;  // need ~322MB

  (void)hipFuncSetAttribute((const void*)qkv256_kernel,
                            hipFuncAttributeMaxDynamicSharedMemorySize, 131072);
  (void)hipFuncSetAttribute((const void*)qk_gemm_kernel,
                            hipFuncAttributeMaxDynamicSharedMemorySize, 65536);
  (void)hipFuncSetAttribute((const void*)pv_gemm_kernel,
                            hipFuncAttributeMaxDynamicSharedMemorySize, 65536);

  cvt_x_kernel<<<dim3((BATCH * SEQ * DIM / 8) / 256), 256, 0, stream>>>(x, Xb);
  wt_kernel<<<dim3(NQKV / 32, DIM / 32), dim3(32, 8), 0, stream>>>(W, Wt);
  qkv256_kernel<<<dim3(1152), dim3(512), 131072, stream>>>(Xb, Wt, bias, qkv, vT);
  qk_gemm_kernel<<<dim3(36, BATCH), 256, 65536, stream>>>(qkv, Smt);
  pv_gemm_kernel<<<dim3(DIM / 128, SEQ / 128, BATCH), 256, 65536, stream>>>(Smt, vT, out);
}